// Round 1
// baseline (256.136 us; speedup 1.0000x reference)
//
#include <hip/hip_runtime.h>

// SphericalBessel: Miller downward recurrence, fp64 internal, fp32 out.
// N=65536, K=32, L=32, lstart = 32 + int(sqrt(320)) = 49.
// out[n, l, k] = y[l] * (sin(x)/x) / y[0] * sqrt(2/pi) * k,  x = r[n]*k.
//
// v2: two-pass recurrence. Pass 1 tracks only the carries to get y[0]
// (no double y[32] array -> ~24 VGPRs instead of ~100+, 8 waves/SIMD,
// no scratch risk). Pass 2 re-runs the bitwise-identical chain and
// scales+stores each term on the fly (stores spread through the loop,
// offsets fold into the store immediate). sin computed via fp32 sinf:
// injects ~3e-5 relative error into the per-thread normalization only,
// ~1.5e-3 of the 2%-of-absmax threshold. The recurrence itself must stay
// fp64: for x > ~45 Miller diverges and the reference is defined by its
// exact fp64 trajectory (near-singular y[0] normalizations).

#define K_MAX 32
#define L_MAX 32
#define LSTART 49  // L_MAX + int(sqrt(10*L_MAX))

__global__ __launch_bounds__(256) void sph_bessel_kernel(
    const float* __restrict__ r, float* __restrict__ out, int n_total) {
    const int tid = blockIdx.x * blockDim.x + threadIdx.x;
    if (tid >= n_total * K_MAX) return;

    const int n  = tid >> 5;   // radius index
    const int kq = tid & 31;   // k index, k = kq+1
    const double kd = (double)(kq + 1);

    const double x   = (double)r[n] * kd;
    const double inv = 1.0 / x;   // reference divides each step; 1 ulp diff is
                                  // benign vs the 2%-of-absmax threshold

    // ---- Pass 1: full downward recurrence, carries only -> y[0]. ----
    double j1 = 1.0, j2 = 0.0;
#pragma unroll
    for (int i = LSTART; i >= 1; --i) {
        const double j0 = fma((2.0 * i + 1.0) * inv, j1, -j2);
        j2 = j1;
        j1 = j0;
    }
    const double y0 = j1;

    // true j_0(x) = sin(x)/x ; fp32 sin is ~3e-5 relative on the
    // normalization — negligible vs threshold. Keep divides in fp64.
    const double true_j0 = (double)sinf((float)x) * inv;
    const double scale   = (true_j0 / y0) * 0.79788456080286535588 * kd;

    // ---- Pass 2: identical chain, scale + store on the fly. ----
    float* op = out + (size_t)n * (L_MAX * K_MAX) + kq;
    j1 = 1.0;
    j2 = 0.0;
#pragma unroll
    for (int i = LSTART; i >= 1; --i) {
        const double j0 = fma((2.0 * i + 1.0) * inv, j1, -j2);
        j2 = j1;
        j1 = j0;
        if (i <= L_MAX) {
            op[(size_t)(i - 1) * K_MAX] = (float)(j0 * scale);
        }
    }
}

extern "C" void kernel_launch(void* const* d_in, const int* in_sizes, int n_in,
                              void* d_out, int out_size, void* d_ws, size_t ws_size,
                              hipStream_t stream) {
    const float* r = (const float*)d_in[0];
    float* out = (float*)d_out;
    const int n_total = in_sizes[0];  // 65536

    const int total_threads = n_total * K_MAX;
    const int block = 256;
    const int grid = (total_threads + block - 1) / block;
    sph_bessel_kernel<<<grid, block, 0, stream>>>(r, out, n_total);
}